// Round 1
// baseline (1844.058 us; speedup 1.0000x reference)
//
#include <hip/hip_runtime.h>
#include <math.h>

// Problem constants (from reference)
#define Bsz 32
#define Tt  10
#define Dd  10
#define Uu  50
#define Pp  50
#define Ee  256

#define SKV_STRIDE 257   // K/V tile stride (odd -> conflict-free lane-varying p reads)
#define SH_STRIDE  260   // H tile stride (multiple of 4 -> float4-aligned rows)
#define SS_STRIDE  52    // score tile stride

__global__ __launch_bounds__(512, 1) void fusion_kernel(
    const float* __restrict__ Q,  const float* __restrict__ K,
    const float* __restrict__ V,  const float* __restrict__ M,
    const float* __restrict__ W1, const float* __restrict__ b1,
    const float* __restrict__ W2, const float* __restrict__ b2,
    const float* __restrict__ ln1w, const float* __restrict__ ln1b,
    const float* __restrict__ ln2w, const float* __restrict__ ln2b,
    float* __restrict__ out)
{
    __shared__ float sKV[Pp * SH_STRIDE];  // 13000 floats: K(stride 257) -> V(stride 257) -> H(stride 260)
    __shared__ float sS [Uu * SS_STRIDE];  // scores
    __shared__ float sX [Uu * Ee];         // post-LN1 activations
    __shared__ float sRed[16];             // per-wave reduction partials

    const int tid  = threadIdx.x;
    const int lane = tid & 63;
    const int wave = tid >> 6;        // 0..7
    const int e    = tid & 255;       // column within E
    const int half = tid >> 8;        // 0 or 1: which 25 rows of U this group owns
    const int u_base = half * 25;

    const int btd = blockIdx.x;
    const int b   = btd / (Tt * Dd);
    const int rem = btd % (Tt * Dd);
    const int t   = rem / Dd;
    const int d   = rem % Dd;

    const float* Qb = Q + ((size_t)(b * Tt + t) * Uu) * Ee;
    const float* Kb = K + ((size_t)(b * Dd + d) * Pp) * Ee;
    const float* Vb = V + ((size_t)(b * Dd + d) * Pp) * Ee;
    const float* Mb = M + ((size_t)((b * Tt + t) * Dd + d) * Uu) * Pp;
    float*       Ob = out + ((size_t)((b * Tt + t) * Dd + d) * Uu) * Ee;

    // ---- P1: stage K into LDS (coalesced) ----
    for (int i = tid; i < Pp * Ee; i += 512) {
        int p = i >> 8, c = i & 255;
        sKV[p * SKV_STRIDE + c] = Kb[i];
    }
    __syncthreads();

    // ---- P2: scores S[u][p] = Q.K/scale + mask, 2x2 register tiles ----
    // scale = sqrt(256)+1e-8 which is exactly 16.0f in fp32
    const float inv_scale = 1.0f / (sqrtf(256.0f) + 1e-8f);
    for (int g = tid; g < 625; g += 512) {
        const int u0 = (g / 25) * 2;
        const int p0 = (g % 25) * 2;
        float a00 = 0.f, a01 = 0.f, a10 = 0.f, a11 = 0.f;
        const float* q0 = Qb + u0 * Ee;
        const float* q1 = Qb + (u0 + 1) * Ee;
        const float* k0 = &sKV[p0 * SKV_STRIDE];
        const float* k1 = &sKV[(p0 + 1) * SKV_STRIDE];
        #pragma unroll 8
        for (int c = 0; c < Ee; ++c) {
            float qa = q0[c], qb = q1[c];
            float ka = k0[c], kb = k1[c];
            a00 += qa * ka; a01 += qa * kb;
            a10 += qb * ka; a11 += qb * kb;
        }
        sS[ u0      * SS_STRIDE + p0    ] = a00 * inv_scale + Mb[ u0      * Pp + p0    ];
        sS[ u0      * SS_STRIDE + p0 + 1] = a01 * inv_scale + Mb[ u0      * Pp + p0 + 1];
        sS[(u0 + 1) * SS_STRIDE + p0    ] = a10 * inv_scale + Mb[(u0 + 1) * Pp + p0    ];
        sS[(u0 + 1) * SS_STRIDE + p0 + 1] = a11 * inv_scale + Mb[(u0 + 1) * Pp + p0 + 1];
    }
    __syncthreads();

    // ---- P4: stage V over K (reads of K done at barrier above) ----
    for (int i = tid; i < Pp * Ee; i += 512) {
        int p = i >> 8, c = i & 255;
        sKV[p * SKV_STRIDE + c] = Vb[i];
    }
    // ---- P3: softmax over P, one row per thread (tiny; only wave 0 works) ----
    if (tid < Uu) {
        float* row = &sS[tid * SS_STRIDE];
        float m = row[0];
        #pragma unroll
        for (int p = 1; p < Pp; ++p) m = fmaxf(m, row[p]);
        float s = 0.f;
        #pragma unroll
        for (int p = 0; p < Pp; ++p) { float ex = expf(row[p] - m); row[p] = ex; s += ex; }
        float inv = 1.0f / s;
        #pragma unroll
        for (int p = 0; p < Pp; ++p) row[p] *= inv;
    }
    __syncthreads();

    // ---- P5: v_att (S @ V) + residual Q + LN1 -> sX ----
    {
        float acc[25];
        #pragma unroll
        for (int i = 0; i < 25; ++i) acc[i] = 0.f;
        for (int p = 0; p < Pp; ++p) {
            float v = sKV[p * SKV_STRIDE + e];          // per-lane, conflict-free
            #pragma unroll
            for (int iu = 0; iu < 25; ++iu)
                acc[iu] += sS[(u_base + iu) * SS_STRIDE + p] * v;  // broadcast
        }
        const float w1v = ln1w[e], b1v = ln1b[e];
        for (int iu = 0; iu < 25; ++iu) {
            const int u = u_base + iu;
            float x = acc[iu] + Qb[u * Ee + e];
            float s1 = x, s2 = x * x;
            #pragma unroll
            for (int o = 32; o; o >>= 1) { s1 += __shfl_down(s1, o, 64); s2 += __shfl_down(s2, o, 64); }
            if (lane == 0) { sRed[wave * 2] = s1; sRed[wave * 2 + 1] = s2; }
            __syncthreads();
            float sum = 0.f, sq = 0.f;
            #pragma unroll
            for (int w = 0; w < 4; ++w) { sum += sRed[(half * 4 + w) * 2]; sq += sRed[(half * 4 + w) * 2 + 1]; }
            __syncthreads();
            const float mu   = sum * (1.0f / 256.0f);
            const float var  = sq  * (1.0f / 256.0f) - mu * mu;
            const float rstd = rsqrtf(var + 1e-5f);
            sX[u * Ee + e] = (x - mu) * rstd * w1v + b1v;
        }
    }
    __syncthreads();

    // ---- P6: H = relu(X @ W1^T + b1) -> sKV reused as H (stride 260) ----
    {
        const int j = e;
        float hacc[25];
        const float bb = b1[j];
        #pragma unroll
        for (int i = 0; i < 25; ++i) hacc[i] = bb;
        const float4* w1r = (const float4*)(W1 + (size_t)j * Ee);
        for (int c4 = 0; c4 < 64; ++c4) {
            const float4 w = w1r[c4];                    // row read once, reused x25
            #pragma unroll
            for (int iu = 0; iu < 25; ++iu) {
                const float4 x = ((const float4*)(sX + (u_base + iu) * Ee))[c4];  // broadcast b128
                hacc[iu] += x.x * w.x + x.y * w.y + x.z * w.z + x.w * w.w;
            }
        }
        #pragma unroll
        for (int iu = 0; iu < 25; ++iu)
            sKV[(u_base + iu) * SH_STRIDE + j] = fmaxf(hacc[iu], 0.f);
    }
    __syncthreads();

    // ---- P7: Y = H @ W2^T + b2 + X, LN2, write out ----
    {
        float yacc[25];
        const float bb = b2[e];
        #pragma unroll
        for (int i = 0; i < 25; ++i) yacc[i] = bb;
        const float4* w2r = (const float4*)(W2 + (size_t)e * Ee);
        for (int c4 = 0; c4 < 64; ++c4) {
            const float4 w = w2r[c4];
            #pragma unroll
            for (int iu = 0; iu < 25; ++iu) {
                const float4 h = ((const float4*)(sKV + (u_base + iu) * SH_STRIDE))[c4];  // broadcast b128
                yacc[iu] += h.x * w.x + h.y * w.y + h.z * w.z + h.w * w.w;
            }
        }
        const float w2v = ln2w[e], b2v = ln2b[e];
        for (int iu = 0; iu < 25; ++iu) {
            const int u = u_base + iu;
            float y = yacc[iu] + sX[u * Ee + e];
            float s1 = y, s2 = y * y;
            #pragma unroll
            for (int o = 32; o; o >>= 1) { s1 += __shfl_down(s1, o, 64); s2 += __shfl_down(s2, o, 64); }
            if (lane == 0) { sRed[wave * 2] = s1; sRed[wave * 2 + 1] = s2; }
            __syncthreads();
            float sum = 0.f, sq = 0.f;
            #pragma unroll
            for (int w = 0; w < 4; ++w) { sum += sRed[(half * 4 + w) * 2]; sq += sRed[(half * 4 + w) * 2 + 1]; }
            __syncthreads();
            const float mu   = sum * (1.0f / 256.0f);
            const float var  = sq  * (1.0f / 256.0f) - mu * mu;
            const float rstd = rsqrtf(var + 1e-5f);
            Ob[u * Ee + e] = (y - mu) * rstd * w2v + b2v;
        }
    }
}

extern "C" void kernel_launch(void* const* d_in, const int* in_sizes, int n_in,
                              void* d_out, int out_size, void* d_ws, size_t ws_size,
                              hipStream_t stream) {
    const float* Q    = (const float*)d_in[0];
    const float* K    = (const float*)d_in[1];
    const float* V    = (const float*)d_in[2];
    const float* M    = (const float*)d_in[3];
    const float* W1   = (const float*)d_in[4];
    const float* b1   = (const float*)d_in[5];
    const float* W2   = (const float*)d_in[6];
    const float* b2   = (const float*)d_in[7];
    const float* ln1w = (const float*)d_in[8];
    const float* ln1b = (const float*)d_in[9];
    const float* ln2w = (const float*)d_in[10];
    const float* ln2b = (const float*)d_in[11];
    float* out = (float*)d_out;

    dim3 grid(Bsz * Tt * Dd);   // 3200 blocks, one per (b,t,d)
    dim3 block(512);
    fusion_kernel<<<grid, block, 0, stream>>>(Q, K, V, M, W1, b1, W2, b2,
                                              ln1w, ln1b, ln2w, ln2b, out);
}

// Round 2
// 692.816 us; speedup vs baseline: 2.6617x; 2.6617x over previous
//
#include <hip/hip_runtime.h>
#include <math.h>

// Problem constants
#define Bsz 32
#define Tt  10
#define Dd  10
#define Uu  50
#define Pp  50
#define Ee  256

typedef __attribute__((ext_vector_type(8))) short bf16x8;   // MFMA A/B frag (4 VGPRs)
typedef __attribute__((ext_vector_type(4))) float f32x4;    // MFMA C/D frag

// ---- LDS strides (elements) ----
#define STQ 264   // bf16 rows for sQ/sK/sXbf/sH: 256 + 8 pad -> 528B rows, 2-way-free frag reads
#define STV 72    // sVt (V transposed) bf16
#define STS 72    // sS scores bf16
#define STL 68    // sL logits f32
#define STX 260   // sXf / sY f32
#define STW 136   // W chunk bf16: 128 cols + 8 pad

// ---- LDS region offsets (bytes). Regions are reused across phases:
//  A [0,69632):      sQ(33792)+sK(33792) -> sL(17408) -> sXf(66560) -> sW(69632) -> sY(66560)
//  B [69632,106496): sVt(36864) -> sH(33792)
//  C [106496,115712): sS(9216)
//  D [115712,149504): sXbf(33792)
#define OFF_QA 0
#define OFF_KA 33792
#define OFF_B  69632
#define OFF_C  106496
#define OFF_D  115712
#define SMEM_TOT 149504

__device__ __forceinline__ unsigned short f2bf(float f) {      // RNE fp32->bf16
    unsigned u = __builtin_bit_cast(unsigned, f);
    u += 0x7fffu + ((u >> 16) & 1u);
    return (unsigned short)(u >> 16);
}
__device__ __forceinline__ float bf2f(unsigned short h) {
    unsigned u = ((unsigned)h) << 16;
    return __builtin_bit_cast(float, u);
}
// Fragment load: A[m][k] (or B[n][k] for transposed-B layouts): lane -> row r0+(lane&15),
// cols c0+(lane>>4)*8 .. +7. Row stride must be mult of 8 elems (16B align for b128).
__device__ __forceinline__ bf16x8 ldfrag(const unsigned short* p, int stride, int r0, int c0, int lane) {
    return *(const bf16x8*)(p + (size_t)(r0 + (lane & 15)) * stride + c0 + ((lane >> 4) << 3));
}

__global__ void convert_w_kernel(const float* __restrict__ W1, const float* __restrict__ W2,
                                 unsigned short* __restrict__ ws) {
    int i4 = (blockIdx.x * 256 + threadIdx.x) * 4;   // 64 blocks x 256 thr x 4 = 65536
    float4 a = *(const float4*)(W1 + i4);
    ushort4 oa; oa.x = f2bf(a.x); oa.y = f2bf(a.y); oa.z = f2bf(a.z); oa.w = f2bf(a.w);
    *(ushort4*)(ws + i4) = oa;
    float4 b = *(const float4*)(W2 + i4);
    ushort4 ob; ob.x = f2bf(b.x); ob.y = f2bf(b.y); ob.z = f2bf(b.z); ob.w = f2bf(b.w);
    *(ushort4*)(ws + 65536 + i4) = ob;
}

__device__ __forceinline__ void stage_w_chunk(unsigned short* sW, const unsigned short* wbf,
                                              const float* Wf, int use_ws, int c0, int tid) {
    if (use_ws) {
        for (int i = tid; i < 4096; i += 512) {          // 256 rows x 128 cols / 8
            int j = i >> 4, cl8 = (i & 15) << 3;
            *(uint4*)(sW + j * STW + cl8) = *(const uint4*)(wbf + j * 256 + c0 + cl8);
        }
    } else {
        for (int i = tid; i < 4096; i += 512) {
            int j = i >> 4, cl8 = (i & 15) << 3;
            const float* s = Wf + j * 256 + c0 + cl8;
            ushort4 lo, hi;
            lo.x = f2bf(s[0]); lo.y = f2bf(s[1]); lo.z = f2bf(s[2]); lo.w = f2bf(s[3]);
            hi.x = f2bf(s[4]); hi.y = f2bf(s[5]); hi.z = f2bf(s[6]); hi.w = f2bf(s[7]);
            *(ushort4*)(sW + j * STW + cl8) = lo;
            *(ushort4*)(sW + j * STW + cl8 + 4) = hi;
        }
    }
}

__global__ __launch_bounds__(512, 1) void fusion_kernel(
    const float* __restrict__ Q,  const float* __restrict__ K,
    const float* __restrict__ V,  const float* __restrict__ Msk,
    const float* __restrict__ W1, const float* __restrict__ b1,
    const float* __restrict__ W2, const float* __restrict__ b2,
    const float* __restrict__ ln1w, const float* __restrict__ ln1b,
    const float* __restrict__ ln2w, const float* __restrict__ ln2b,
    const unsigned short* __restrict__ wsbf, int use_ws,
    float* __restrict__ out)
{
    __shared__ __align__(16) unsigned char smem[SMEM_TOT];
    unsigned short* sQ   = (unsigned short*)(smem + OFF_QA);
    unsigned short* sK   = (unsigned short*)(smem + OFF_KA);
    unsigned short* sVt  = (unsigned short*)(smem + OFF_B);
    unsigned short* sS   = (unsigned short*)(smem + OFF_C);
    unsigned short* sXbf = (unsigned short*)(smem + OFF_D);
    unsigned short* sH   = (unsigned short*)(smem + OFF_B);   // aliases sVt (dead after PV)
    unsigned short* sW   = (unsigned short*)(smem + OFF_QA);  // aliases sQ+sK (dead after scores)
    float* sL = (float*)(smem + OFF_QA);                      // logits, aliases sQ
    float* sXf = (float*)(smem + OFF_QA);                     // pre-LN1 x, aliases sQ+sK
    float* sY  = (float*)(smem + OFF_QA);                     // pre-LN2 y, aliases sW

    const int tid  = threadIdx.x;
    const int lane = tid & 63;
    const int wave = tid >> 6;       // 0..7
    const int quad = lane >> 4;      // 0..3 (C/D row group)
    const int l15  = lane & 15;      // C/D col within tile

    const int btd = blockIdx.x;
    const int b   = btd / (Tt * Dd);
    const int rem = btd % (Tt * Dd);
    const int t   = rem / Dd;
    const int d   = rem % Dd;

    const float* Qb = Q + ((size_t)(b * Tt + t) * Uu) * Ee;
    const float* Kb = K + ((size_t)(b * Dd + d) * Pp) * Ee;
    const float* Vb = V + ((size_t)(b * Dd + d) * Pp) * Ee;
    const float* Mb = Msk + ((size_t)((b * Tt + t) * Dd + d) * Uu) * Pp;
    float*       Ob = out + ((size_t)((b * Tt + t) * Dd + d) * Uu) * Ee;

    // ================= Phase A: stage Q,K (bf16 rows) and V^T into LDS =================
    for (int i = tid; i < 3200; i += 512) {               // 50 rows x 64 float4
        int r = i >> 6, c4 = (i & 63) << 2;
        float4 q = *(const float4*)(Qb + r * Ee + c4);
        ushort4 o; o.x = f2bf(q.x); o.y = f2bf(q.y); o.z = f2bf(q.z); o.w = f2bf(q.w);
        *(ushort4*)(sQ + r * STQ + c4) = o;
        float4 k = *(const float4*)(Kb + r * Ee + c4);
        ushort4 ok; ok.x = f2bf(k.x); ok.y = f2bf(k.y); ok.z = f2bf(k.z); ok.w = f2bf(k.w);
        *(ushort4*)(sK + r * STQ + c4) = ok;
        float4 v = *(const float4*)(Vb + r * Ee + c4);
        sVt[(c4 + 0) * STV + r] = f2bf(v.x);
        sVt[(c4 + 1) * STV + r] = f2bf(v.y);
        sVt[(c4 + 2) * STV + r] = f2bf(v.z);
        sVt[(c4 + 3) * STV + r] = f2bf(v.w);
    }
    // zero pad rows 50..63 of sQ,sK (A/B pad) and cols 50..63 of sVt (PV K-pad)
    for (int i = tid; i < 924; i += 512) {                // 14 rows x 66 ushort4
        int r = 50 + i / 66, c = (i % 66) << 2;
        ushort4 z = {0, 0, 0, 0};
        *(ushort4*)(sQ + r * STQ + c) = z;
        *(ushort4*)(sK + r * STQ + c) = z;
    }
    for (int i = tid; i < 3584; i += 512) {               // 256 e-rows x 14 p-pads
        int e = i / 14, p = 50 + (i % 14);
        sVt[e * STV + p] = 0;
    }
    __syncthreads();

    // ================= Scores GEMM: S = Q.K^T (M=64,N=64,K=256) =================
    // wave w: m-tile = w>>1, n-tiles = (w&1)*2 + {0,1}
    {
        const int m0  = (wave >> 1) << 4;
        const int n0a = ((wave & 1) << 5);
        const int n0b = n0a + 16;
        f32x4 acc0 = {0.f, 0.f, 0.f, 0.f}, acc1 = {0.f, 0.f, 0.f, 0.f};
        #pragma unroll
        for (int k0 = 0; k0 < 256; k0 += 32) {
            bf16x8 a  = ldfrag(sQ, STQ, m0, k0, lane);
            bf16x8 b0 = ldfrag(sK, STQ, n0a, k0, lane);
            bf16x8 b1f = ldfrag(sK, STQ, n0b, k0, lane);
            acc0 = __builtin_amdgcn_mfma_f32_16x16x32_bf16(a, b0, acc0, 0, 0, 0);
            acc1 = __builtin_amdgcn_mfma_f32_16x16x32_bf16(a, b1f, acc1, 0, 0, 0);
        }
        __syncthreads();   // all MFMA reads of sQ/sK done before sL overwrites region A
        const float inv_scale = 1.0f / (sqrtf(256.0f) + 1e-8f);
        #pragma unroll
        for (int r = 0; r < 4; ++r) {
            int u = m0 + (quad << 2) + r;
            if (u < Uu) {
                int pa = n0a + l15, pb = n0b + l15;
                float va = acc0[r] * inv_scale;
                float vb = acc1[r] * inv_scale;
                if (pa < Pp) va += Mb[u * Pp + pa];
                if (pb < Pp) vb += Mb[u * Pp + pb];
                sL[u * STL + pa] = va;
                sL[u * STL + pb] = vb;
            }
        }
    }
    __syncthreads();

    // ================= Softmax over p (rows 0..49), write bf16 A-layout to sS =================
    if (tid < 64) {
        int u = tid;
        if (u < Uu) {
            float mx = -1e30f;
            #pragma unroll 10
            for (int p = 0; p < Pp; ++p) mx = fmaxf(mx, sL[u * STL + p]);
            float sum = 0.f;
            float ex[Pp];
            #pragma unroll 10
            for (int p = 0; p < Pp; ++p) { ex[p] = expf(sL[u * STL + p] - mx); sum += ex[p]; }
            float inv = 1.0f / sum;
            #pragma unroll 10
            for (int p = 0; p < Pp; ++p) sS[u * STS + p] = f2bf(ex[p] * inv);
            #pragma unroll
            for (int p = Pp; p < 64; ++p) sS[u * STS + p] = 0;
        } else {
            for (int p = 0; p < 64; ++p) sS[u * STS + p] = 0;
        }
    }
    __syncthreads();

    // ================= PV GEMM: v_att = S.V (M=64,N=256,K=64) + Q residual -> sXf =================
    // wave w: m-tile = w>>1, n-half = w&1 (8 n-tiles of 16)
    {
        const int m0 = (wave >> 1) << 4;
        const int nh = (wave & 1) * 128;
        f32x4 acc[8];
        #pragma unroll
        for (int i = 0; i < 8; ++i) acc[i] = (f32x4){0.f, 0.f, 0.f, 0.f};
        #pragma unroll
        for (int k0 = 0; k0 < 64; k0 += 32) {
            bf16x8 a = ldfrag(sS, STS, m0, k0, lane);
            #pragma unroll
            for (int nt = 0; nt < 8; ++nt) {
                bf16x8 bfr = ldfrag(sVt, STV, nh + (nt << 4), k0, lane);
                acc[nt] = __builtin_amdgcn_mfma_f32_16x16x32_bf16(a, bfr, acc[nt], 0, 0, 0);
            }
        }
        // epilogue: x = v_att + Q  (writes region A: sQ/sK/sL all dead; no overlap with sS/sVt)
        #pragma unroll
        for (int nt = 0; nt < 8; ++nt) {
            int e = nh + (nt << 4) + l15;
            #pragma unroll
            for (int r = 0; r < 4; ++r) {
                int u = m0 + (quad << 2) + r;
                if (u < Uu) sXf[u * STX + e] = acc[nt][r] + Qb[u * Ee + e];
            }
        }
    }
    __syncthreads();

    // ================= LN1 -> sXbf (bf16, zero-padded rows) =================
    {
        const float4 w4 = *(const float4*)(ln1w + (lane << 2));
        const float4 b4 = *(const float4*)(ln1b + (lane << 2));
        #pragma unroll
        for (int r = 0; r < 8; ++r) {
            int row = (wave << 3) + r;
            if (row < Uu) {
                f32x4 x = *(const f32x4*)(sXf + row * STX + (lane << 2));
                float s1 = x[0] + x[1] + x[2] + x[3];
                float s2 = x[0]*x[0] + x[1]*x[1] + x[2]*x[2] + x[3]*x[3];
                #pragma unroll
                for (int m = 32; m; m >>= 1) { s1 += __shfl_xor(s1, m, 64); s2 += __shfl_xor(s2, m, 64); }
                float mu = s1 * (1.0f / 256.0f);
                float var = s2 * (1.0f / 256.0f) - mu * mu;
                float rstd = rsqrtf(var + 1e-5f);
                ushort4 o;
                o.x = f2bf((x[0] - mu) * rstd * w4.x + b4.x);
                o.y = f2bf((x[1] - mu) * rstd * w4.y + b4.y);
                o.z = f2bf((x[2] - mu) * rstd * w4.z + b4.z);
                o.w = f2bf((x[3] - mu) * rstd * w4.w + b4.w);
                *(ushort4*)(sXbf + row * STQ + (lane << 2)) = o;
            } else {
                ushort4 z = {0, 0, 0, 0};
                *(ushort4*)(sXbf + row * STQ + (lane << 2)) = z;
            }
        }
    }
    __syncthreads();

    // ================= FFN1: H = relu(X.W1^T + b1) (M=64,N=256,K=256) -> sH =================
    {
        const int m0 = (wave >> 1) << 4;
        const int nh = (wave & 1) * 128;
        f32x4 acc[8];
        #pragma unroll
        for (int i = 0; i < 8; ++i) acc[i] = (f32x4){0.f, 0.f, 0.f, 0.f};
        for (int c0 = 0; c0 < 256; c0 += 128) {
            stage_w_chunk(sW, wsbf, W1, use_ws, c0, tid);
            __syncthreads();
            #pragma unroll
            for (int kk = 0; kk < 128; kk += 32) {
                bf16x8 a = ldfrag(sXbf, STQ, m0, c0 + kk, lane);
                #pragma unroll
                for (int nt = 0; nt < 8; ++nt) {
                    bf16x8 bfr = ldfrag(sW, STW, nh + (nt << 4), kk, lane);
                    acc[nt] = __builtin_amdgcn_mfma_f32_16x16x32_bf16(a, bfr, acc[nt], 0, 0, 0);
                }
            }
            __syncthreads();   // before next chunk overwrites sW
        }
        #pragma unroll
        for (int nt = 0; nt < 8; ++nt) {
            int j = nh + (nt << 4) + l15;
            float bb = b1[j];
            #pragma unroll
            for (int r = 0; r < 4; ++r) {
                int u = m0 + (quad << 2) + r;
                sH[u * STQ + j] = f2bf(fmaxf(acc[nt][r] + bb, 0.f));
            }
        }
    }
    __syncthreads();

    // ================= FFN2: Y = H.W2^T + b2 + X (M=64,N=256,K=256) -> sY, LN2 -> out =================
    {
        const int m0 = (wave >> 1) << 4;
        const int nh = (wave & 1) * 128;
        f32x4 acc[8];
        #pragma unroll
        for (int i = 0; i < 8; ++i) acc[i] = (f32x4){0.f, 0.f, 0.f, 0.f};
        for (int c0 = 0; c0 < 256; c0 += 128) {
            stage_w_chunk(sW, wsbf + 65536, W2, use_ws, c0, tid);
            __syncthreads();
            #pragma unroll
            for (int kk = 0; kk < 128; kk += 32) {
                bf16x8 a = ldfrag(sH, STQ, m0, c0 + kk, lane);
                #pragma unroll
                for (int nt = 0; nt < 8; ++nt) {
                    bf16x8 bfr = ldfrag(sW, STW, nh + (nt << 4), kk, lane);
                    acc[nt] = __builtin_amdgcn_mfma_f32_16x16x32_bf16(a, bfr, acc[nt], 0, 0, 0);
                }
            }
            __syncthreads();   // all sW reads done (also before sY epilogue overwrites region A)
        }
        #pragma unroll
        for (int nt = 0; nt < 8; ++nt) {
            int e = nh + (nt << 4) + l15;
            float bb = b2[e];
            #pragma unroll
            for (int r = 0; r < 4; ++r) {
                int u = m0 + (quad << 2) + r;
                if (u < Uu) sY[u * STX + e] = acc[nt][r] + bb + bf2f(sXbf[u * STQ + e]);
            }
        }
    }
    __syncthreads();

    // ================= LN2 -> global out =================
    {
        const float4 w4 = *(const float4*)(ln2w + (lane << 2));
        const float4 b4 = *(const float4*)(ln2b + (lane << 2));
        #pragma unroll
        for (int r = 0; r < 8; ++r) {
            int row = (wave << 3) + r;
            if (row < Uu) {
                f32x4 y = *(const f32x4*)(sY + row * STX + (lane << 2));
                float s1 = y[0] + y[1] + y[2] + y[3];
                float s2 = y[0]*y[0] + y[1]*y[1] + y[2]*y[2] + y[3]*y[3];
                #pragma unroll
                for (int m = 32; m; m >>= 1) { s1 += __shfl_xor(s1, m, 64); s2 += __shfl_xor(s2, m, 64); }
                float mu = s1 * (1.0f / 256.0f);
                float var = s2 * (1.0f / 256.0f) - mu * mu;
                float rstd = rsqrtf(var + 1e-5f);
                float4 o;
                o.x = (y[0] - mu) * rstd * w4.x + b4.x;
                o.y = (y[1] - mu) * rstd * w4.y + b4.y;
                o.z = (y[2] - mu) * rstd * w4.z + b4.z;
                o.w = (y[3] - mu) * rstd * w4.w + b4.w;
                *(float4*)(Ob + row * Ee + (lane << 2)) = o;
            }
        }
    }
}

extern "C" void kernel_launch(void* const* d_in, const int* in_sizes, int n_in,
                              void* d_out, int out_size, void* d_ws, size_t ws_size,
                              hipStream_t stream) {
    const float* Q    = (const float*)d_in[0];
    const float* K    = (const float*)d_in[1];
    const float* V    = (const float*)d_in[2];
    const float* M    = (const float*)d_in[3];
    const float* W1   = (const float*)d_in[4];
    const float* b1   = (const float*)d_in[5];
    const float* W2   = (const float*)d_in[6];
    const float* b2   = (const float*)d_in[7];
    const float* ln1w = (const float*)d_in[8];
    const float* ln1b = (const float*)d_in[9];
    const float* ln2w = (const float*)d_in[10];
    const float* ln2b = (const float*)d_in[11];
    float* out = (float*)d_out;

    int use_ws = (ws_size >= 262144) ? 1 : 0;
    const unsigned short* wsbf = (const unsigned short*)d_ws;
    if (use_ws) {
        convert_w_kernel<<<64, 256, 0, stream>>>(W1, W2, (unsigned short*)d_ws);
    }
    fusion_kernel<<<Bsz * Tt * Dd, 512, 0, stream>>>(Q, K, V, M, W1, b1, W2, b2,
                                                     ln1w, ln1b, ln2w, ln2b,
                                                     wsbf, use_ws, out);
}

// Round 3
// 599.962 us; speedup vs baseline: 3.0736x; 1.1548x over previous
//
#include <hip/hip_runtime.h>
#include <math.h>

#define Bsz 32
#define Tt  10
#define Dd  10
#define Uu  50
#define Pp  50
#define Ee  256

typedef __attribute__((ext_vector_type(8))) short bf16x8;   // MFMA A/B frag
typedef __attribute__((ext_vector_type(4))) float f32x4;    // MFMA C/D frag

#define STK 264   // sK / sXbf / sH row stride (halfwords): 256+8, 16B-aligned rows, stride/8 odd
#define STV 72    // sVt row stride
#define STS 72    // sS row stride

// LDS regions (bytes), aliased across phases:
//  A [0,33792):      sK (scores B)        -> sXbf (post-LN1, bf16)
//  B [33792,70656):  sVt (PV B, V^T)      -> sH (post-relu, bf16)
//  C [70656,79872):  sS (softmax P, bf16) -> red2 f32[64][4][2] (LN2 partials)
//  R [79872,80896):  red f32[64][2][2]    (LN1 partials)
#define OFF_A 0
#define OFF_B 33792
#define OFF_C 70656
#define OFF_R 79872
#define SMEM_TOT 80896   // 79 KiB -> 2 blocks/CU

__device__ __forceinline__ unsigned short f2bf(float f) {      // RNE fp32->bf16
    unsigned u = __builtin_bit_cast(unsigned, f);
    u += 0x7fffu + ((u >> 16) & 1u);
    return (unsigned short)(u >> 16);
}
__device__ __forceinline__ float bf2f(unsigned short h) {
    unsigned u = ((unsigned)h) << 16;
    return __builtin_bit_cast(float, u);
}
// A/B fragment from LDS: lane q*16+l15 -> row r0+l15, cols c0+q*8..+7 (b128)
__device__ __forceinline__ bf16x8 ldfrag(const unsigned short* p, int stride, int r0, int c0, int lane) {
    return *(const bf16x8*)(p + (size_t)(r0 + (lane & 15)) * stride + c0 + ((lane >> 4) << 3));
}
// W fragment straight from global (bf16 ws if available, else fp32 + convert)
__device__ __forceinline__ bf16x8 wfrag(const unsigned short* wbf, const float* wf, int use_ws,
                                        int n, int k0, int lane) {
    const int row = n + (lane & 15);
    const int col = k0 + ((lane >> 4) << 3);
    if (use_ws) {
        return *(const bf16x8*)(wbf + (size_t)row * 256 + col);
    }
    const float4 a = *(const float4*)(wf + (size_t)row * 256 + col);
    const float4 b = *(const float4*)(wf + (size_t)row * 256 + col + 4);
    bf16x8 r;
    r[0] = (short)f2bf(a.x); r[1] = (short)f2bf(a.y); r[2] = (short)f2bf(a.z); r[3] = (short)f2bf(a.w);
    r[4] = (short)f2bf(b.x); r[5] = (short)f2bf(b.y); r[6] = (short)f2bf(b.z); r[7] = (short)f2bf(b.w);
    return r;
}

__global__ void convert_w_kernel(const float* __restrict__ W1, const float* __restrict__ W2,
                                 unsigned short* __restrict__ ws) {
    int i4 = (blockIdx.x * 256 + threadIdx.x) * 4;
    float4 a = *(const float4*)(W1 + i4);
    ushort4 oa; oa.x = f2bf(a.x); oa.y = f2bf(a.y); oa.z = f2bf(a.z); oa.w = f2bf(a.w);
    *(ushort4*)(ws + i4) = oa;
    float4 b = *(const float4*)(W2 + i4);
    ushort4 ob; ob.x = f2bf(b.x); ob.y = f2bf(b.y); ob.z = f2bf(b.z); ob.w = f2bf(b.w);
    *(ushort4*)(ws + 65536 + i4) = ob;
}

__global__ __launch_bounds__(512, 4) void fusion_kernel(
    const float* __restrict__ Q,  const float* __restrict__ K,
    const float* __restrict__ V,  const float* __restrict__ Msk,
    const float* __restrict__ W1, const float* __restrict__ b1,
    const float* __restrict__ W2, const float* __restrict__ b2,
    const float* __restrict__ ln1w, const float* __restrict__ ln1b,
    const float* __restrict__ ln2w, const float* __restrict__ ln2b,
    const unsigned short* __restrict__ wsbf, int use_ws,
    float* __restrict__ out)
{
    __shared__ __align__(16) unsigned char smem[SMEM_TOT];
    unsigned short* sK   = (unsigned short*)(smem + OFF_A);
    unsigned short* sXbf = (unsigned short*)(smem + OFF_A);
    unsigned short* sVt  = (unsigned short*)(smem + OFF_B);
    unsigned short* sH   = (unsigned short*)(smem + OFF_B);
    unsigned short* sS   = (unsigned short*)(smem + OFF_C);
    float*          red2 = (float*)(smem + OFF_C);   // [u][nq][2]
    float*          red  = (float*)(smem + OFF_R);   // [u][half][2]

    const int tid  = threadIdx.x;
    const int lane = tid & 63;
    const int wave = tid >> 6;
    const int quad = lane >> 4;
    const int l15  = lane & 15;

    const int btd = blockIdx.x;
    const int b   = btd / (Tt * Dd);
    const int rem = btd % (Tt * Dd);
    const int t   = rem / Dd;
    const int d   = rem % Dd;

    const float* Qb = Q + ((size_t)(b * Tt + t) * Uu) * Ee;
    const float* Kb = K + ((size_t)(b * Dd + d) * Pp) * Ee;
    const float* Vb = V + ((size_t)(b * Dd + d) * Pp) * Ee;
    const float* Mb = Msk + ((size_t)((b * Tt + t) * Dd + d) * Uu) * Pp;
    float*       Ob = out + ((size_t)((b * Tt + t) * Dd + d) * Uu) * Ee;

    // ---- Stage K (all waves, coalesced) ----
    for (int i = tid; i < 3200; i += 512) {
        int r = i >> 6, c4 = (i & 63) << 2;
        float4 k = *(const float4*)(Kb + r * Ee + c4);
        ushort4 ok; ok.x = f2bf(k.x); ok.y = f2bf(k.y); ok.z = f2bf(k.z); ok.w = f2bf(k.w);
        *(ushort4*)(sK + r * STK + c4) = ok;
    }
    for (int i = tid; i < 924; i += 512) {     // zero rows 50..63 (14 x 66 ushort4)
        int r = 50 + i / 66, c = (i % 66) << 2;
        ushort4 z = {0, 0, 0, 0};
        *(ushort4*)(sK + r * STK + c) = z;
    }
    __syncthreads();   // B1

    if (wave < 4) {
        // ---- Scores m-tile = wave: Q from global, K^T from LDS, softmax in registers ----
        const int mt = wave;
        int arow = mt * 16 + l15; if (arow > 49) arow = 49;   // clamp: garbage rows stay finite
        const float* qrow = Qb + (size_t)arow * Ee + (quad << 3);
        f32x4 acc[4];
        #pragma unroll
        for (int i = 0; i < 4; ++i) acc[i] = (f32x4){0.f, 0.f, 0.f, 0.f};
        #pragma unroll
        for (int k0 = 0; k0 < 256; k0 += 32) {
            float4 qa = *(const float4*)(qrow + k0);
            float4 qb = *(const float4*)(qrow + k0 + 4);
            bf16x8 a;
            a[0] = (short)f2bf(qa.x); a[1] = (short)f2bf(qa.y); a[2] = (short)f2bf(qa.z); a[3] = (short)f2bf(qa.w);
            a[4] = (short)f2bf(qb.x); a[5] = (short)f2bf(qb.y); a[6] = (short)f2bf(qb.z); a[7] = (short)f2bf(qb.w);
            #pragma unroll
            for (int nt = 0; nt < 4; ++nt) {
                bf16x8 bf = ldfrag(sK, STK, nt << 4, k0, lane);
                acc[nt] = __builtin_amdgcn_mfma_f32_16x16x32_bf16(a, bf, acc[nt], 0, 0, 0);
            }
        }
        // logits: scale (sqrt(256)+1e-8 == 16.0f in fp32) + mask; p>=50 -> -inf-ish
        float l[4][4];
        #pragma unroll
        for (int nt = 0; nt < 4; ++nt) {
            int p = (nt << 4) + l15;
            #pragma unroll
            for (int r = 0; r < 4; ++r) {
                int u = mt * 16 + (quad << 2) + r;
                float v = acc[nt][r] * 0.0625f;
                if (p < Pp) { if (u < Uu) v += Mb[u * Pp + p]; }
                else v = -1e30f;
                l[nt][r] = v;
            }
        }
        #pragma unroll
        for (int r = 0; r < 4; ++r) {
            float m = fmaxf(fmaxf(l[0][r], l[1][r]), fmaxf(l[2][r], l[3][r]));
            #pragma unroll
            for (int msk = 1; msk < 16; msk <<= 1) m = fmaxf(m, __shfl_xor(m, msk));
            float e0 = __expf(l[0][r] - m), e1 = __expf(l[1][r] - m);
            float e2 = __expf(l[2][r] - m), e3 = __expf(l[3][r] - m);
            float s = e0 + e1 + e2 + e3;
            #pragma unroll
            for (int msk = 1; msk < 16; msk <<= 1) s += __shfl_xor(s, msk);
            float inv = 1.0f / s;
            int u = mt * 16 + (quad << 2) + r;
            sS[u * STS +  0 + l15] = f2bf(e0 * inv);
            sS[u * STS + 16 + l15] = f2bf(e1 * inv);
            sS[u * STS + 32 + l15] = f2bf(e2 * inv);
            sS[u * STS + 48 + l15] = f2bf(e3 * inv);
        }
    } else {
        // ---- Waves 4-7: stage V^T (e per lane: 8-way not 32-way conflicts), overlaps scores ----
        const int lt = tid - 256;
        #pragma unroll 4
        for (int i = lt; i < 12800; i += 256) {
            int p = i >> 8, e = i & 255;
            sVt[e * STV + p] = f2bf(Vb[p * Ee + e]);
        }
        for (int i = lt; i < 3584; i += 256) {   // zero k-pad cols p=50..63
            int p = 50 + (i >> 8), e = i & 255;
            sVt[e * STV + p] = 0;
        }
    }
    __syncthreads();   // B2

    // ---- PV: v_att = S.V (all 8 waves: m-tile = w>>1, n-half = w&1) + Q residual + LN1 partials ----
    {
        const int mt = wave >> 1;
        const int nh = (wave & 1) << 7;
        f32x4 acc[8];
        #pragma unroll
        for (int i = 0; i < 8; ++i) acc[i] = (f32x4){0.f, 0.f, 0.f, 0.f};
        #pragma unroll
        for (int k0 = 0; k0 < 64; k0 += 32) {
            bf16x8 a = ldfrag(sS, STS, mt << 4, k0, lane);
            #pragma unroll
            for (int nt = 0; nt < 8; ++nt) {
                bf16x8 bf = ldfrag(sVt, STV, nh + (nt << 4), k0, lane);
                acc[nt] = __builtin_amdgcn_mfma_f32_16x16x32_bf16(a, bf, acc[nt], 0, 0, 0);
            }
        }
        float s1[4] = {0.f, 0.f, 0.f, 0.f}, s2[4] = {0.f, 0.f, 0.f, 0.f};
        #pragma unroll
        for (int nt = 0; nt < 8; ++nt) {
            int e = nh + (nt << 4) + l15;
            #pragma unroll
            for (int r = 0; r < 4; ++r) {
                int u = (mt << 4) + (quad << 2) + r;
                float x = 0.f;
                if (u < Uu) x = acc[nt][r] + Qb[(size_t)u * Ee + e];   // guard: no OOB Q read
                acc[nt][r] = x;
                s1[r] += x; s2[r] += x * x;
            }
        }
        #pragma unroll
        for (int msk = 1; msk < 16; msk <<= 1) {
            #pragma unroll
            for (int r = 0; r < 4; ++r) { s1[r] += __shfl_xor(s1[r], msk); s2[r] += __shfl_xor(s2[r], msk); }
        }
        if (l15 == 0) {
            #pragma unroll
            for (int r = 0; r < 4; ++r) {
                int u = (mt << 4) + (quad << 2) + r;
                red[u * 4 + (wave & 1) * 2 + 0] = s1[r];
                red[u * 4 + (wave & 1) * 2 + 1] = s2[r];
            }
        }
        __syncthreads();   // B3
        float mu[4], rstd[4];
        #pragma unroll
        for (int r = 0; r < 4; ++r) {
            int u = (mt << 4) + (quad << 2) + r;
            float sum = red[u * 4 + 0] + red[u * 4 + 2];
            float sq  = red[u * 4 + 1] + red[u * 4 + 3];
            mu[r] = sum * (1.0f / 256.0f);
            float var = sq * (1.0f / 256.0f) - mu[r] * mu[r];
            rstd[r] = rsqrtf(var + 1e-5f);
        }
        __syncthreads();   // B4 (red reads done; sXbf overwrite of sK region is safe: sK dead)
        #pragma unroll
        for (int nt = 0; nt < 8; ++nt) {
            int e = nh + (nt << 4) + l15;
            float wv = ln1w[e], bv = ln1b[e];
            #pragma unroll
            for (int r = 0; r < 4; ++r) {
                int u = (mt << 4) + (quad << 2) + r;
                float o = (u < Uu) ? ((acc[nt][r] - mu[r]) * rstd[r] * wv + bv) : 0.f;
                sXbf[u * STK + e] = f2bf(o);
            }
        }
    }
    __syncthreads();   // B5

    // ---- FFN1: H = relu(X.W1^T + b1); wave = (m-pair, n-quarter); W frags direct from L2 ----
    const int mp = wave >> 2;     // m-tiles {2mp, 2mp+1}
    const int nq = wave & 3;      // n-tiles 4nq..4nq+3
    {
        f32x4 acc2[2][4];
        #pragma unroll
        for (int mi = 0; mi < 2; ++mi)
            #pragma unroll
            for (int nt = 0; nt < 4; ++nt) acc2[mi][nt] = (f32x4){0.f, 0.f, 0.f, 0.f};
        float b1v[4];
        #pragma unroll
        for (int nt = 0; nt < 4; ++nt) b1v[nt] = b1[(nq << 6) + (nt << 4) + l15];
        #pragma unroll
        for (int k0 = 0; k0 < 256; k0 += 32) {
            bf16x8 a0 = ldfrag(sXbf, STK, (mp << 5),      k0, lane);
            bf16x8 a1 = ldfrag(sXbf, STK, (mp << 5) + 16, k0, lane);
            #pragma unroll
            for (int nt = 0; nt < 4; ++nt) {
                bf16x8 bf = wfrag(wsbf, W1, use_ws, (nq << 6) + (nt << 4), k0, lane);
                acc2[0][nt] = __builtin_amdgcn_mfma_f32_16x16x32_bf16(a0, bf, acc2[0][nt], 0, 0, 0);
                acc2[1][nt] = __builtin_amdgcn_mfma_f32_16x16x32_bf16(a1, bf, acc2[1][nt], 0, 0, 0);
            }
        }
        #pragma unroll
        for (int mi = 0; mi < 2; ++mi)
            #pragma unroll
            for (int nt = 0; nt < 4; ++nt) {
                int j = (nq << 6) + (nt << 4) + l15;
                #pragma unroll
                for (int r = 0; r < 4; ++r) {
                    int u = (mp << 5) + (mi << 4) + (quad << 2) + r;
                    sH[u * STK + j] = f2bf(fmaxf(acc2[mi][nt][r] + b1v[nt], 0.f));
                }
            }
    }
    __syncthreads();   // B6

    // ---- FFN2: Y = H.W2^T + b2 + X; LN2; store ----
    {
        f32x4 acc2[2][4];
        #pragma unroll
        for (int mi = 0; mi < 2; ++mi)
            #pragma unroll
            for (int nt = 0; nt < 4; ++nt) acc2[mi][nt] = (f32x4){0.f, 0.f, 0.f, 0.f};
        float b2v[4], w2l[4], b2l[4];
        #pragma unroll
        for (int nt = 0; nt < 4; ++nt) {
            int j = (nq << 6) + (nt << 4) + l15;
            b2v[nt] = b2[j]; w2l[nt] = ln2w[j]; b2l[nt] = ln2b[j];
        }
        #pragma unroll
        for (int k0 = 0; k0 < 256; k0 += 32) {
            bf16x8 a0 = ldfrag(sH, STK, (mp << 5),      k0, lane);
            bf16x8 a1 = ldfrag(sH, STK, (mp << 5) + 16, k0, lane);
            #pragma unroll
            for (int nt = 0; nt < 4; ++nt) {
                bf16x8 bf = wfrag(wsbf + 65536, W2, use_ws, (nq << 6) + (nt << 4), k0, lane);
                acc2[0][nt] = __builtin_amdgcn_mfma_f32_16x16x32_bf16(a0, bf, acc2[0][nt], 0, 0, 0);
                acc2[1][nt] = __builtin_amdgcn_mfma_f32_16x16x32_bf16(a1, bf, acc2[1][nt], 0, 0, 0);
            }
        }
        // y = ffn2 + b2 + residual X; per-row partial sums over this wave's 64 cols
        float s1[2][4], s2[2][4];
        #pragma unroll
        for (int mi = 0; mi < 2; ++mi)
            #pragma unroll
            for (int r = 0; r < 4; ++r) { s1[mi][r] = 0.f; s2[mi][r] = 0.f; }
        #pragma unroll
        for (int mi = 0; mi < 2; ++mi)
            #pragma unroll
            for (int nt = 0; nt < 4; ++nt) {
                int j = (nq << 6) + (nt << 4) + l15;
                #pragma unroll
                for (int r = 0; r < 4; ++r) {
                    int u = (mp << 5) + (mi << 4) + (quad << 2) + r;
                    float y = acc2[mi][nt][r] + b2v[nt] + bf2f(sXbf[u * STK + j]);
                    acc2[mi][nt][r] = y;
                    s1[mi][r] += y; s2[mi][r] += y * y;
                }
            }
        #pragma unroll
        for (int msk = 1; msk < 16; msk <<= 1)
            #pragma unroll
            for (int mi = 0; mi < 2; ++mi)
                #pragma unroll
                for (int r = 0; r < 4; ++r) {
                    s1[mi][r] += __shfl_xor(s1[mi][r], msk);
                    s2[mi][r] += __shfl_xor(s2[mi][r], msk);
                }
        if (l15 == 0) {
            #pragma unroll
            for (int mi = 0; mi < 2; ++mi)
                #pragma unroll
                for (int r = 0; r < 4; ++r) {
                    int u = (mp << 5) + (mi << 4) + (quad << 2) + r;
                    red2[u * 8 + nq * 2 + 0] = s1[mi][r];
                    red2[u * 8 + nq * 2 + 1] = s2[mi][r];
                }
        }
        __syncthreads();   // B7
        #pragma unroll
        for (int mi = 0; mi < 2; ++mi)
            #pragma unroll
            for (int r = 0; r < 4; ++r) {
                int u = (mp << 5) + (mi << 4) + (quad << 2) + r;
                if (u < Uu) {
                    float sum = red2[u * 8 + 0] + red2[u * 8 + 2] + red2[u * 8 + 4] + red2[u * 8 + 6];
                    float sq  = red2[u * 8 + 1] + red2[u * 8 + 3] + red2[u * 8 + 5] + red2[u * 8 + 7];
                    float mu = sum * (1.0f / 256.0f);
                    float var = sq * (1.0f / 256.0f) - mu * mu;
                    float rstd = rsqrtf(var + 1e-5f);
                    #pragma unroll
                    for (int nt = 0; nt < 4; ++nt) {
                        int j = (nq << 6) + (nt << 4) + l15;
                        Ob[(size_t)u * Ee + j] = (acc2[mi][nt][r] - mu) * rstd * w2l[nt] + b2l[nt];
                    }
                }
            }
    }
}

extern "C" void kernel_launch(void* const* d_in, const int* in_sizes, int n_in,
                              void* d_out, int out_size, void* d_ws, size_t ws_size,
                              hipStream_t stream) {
    const float* Q    = (const float*)d_in[0];
    const float* K    = (const float*)d_in[1];
    const float* V    = (const float*)d_in[2];
    const float* M    = (const float*)d_in[3];
    const float* W1   = (const float*)d_in[4];
    const float* b1   = (const float*)d_in[5];
    const float* W2   = (const float*)d_in[6];
    const float* b2   = (const float*)d_in[7];
    const float* ln1w = (const float*)d_in[8];
    const float* ln1b = (const float*)d_in[9];
    const float* ln2w = (const float*)d_in[10];
    const float* ln2b = (const float*)d_in[11];
    float* out = (float*)d_out;

    int use_ws = (ws_size >= 262144) ? 1 : 0;
    const unsigned short* wsbf = (const unsigned short*)d_ws;
    if (use_ws) {
        convert_w_kernel<<<64, 256, 0, stream>>>(W1, W2, (unsigned short*)d_ws);
    }
    fusion_kernel<<<Bsz * Tt * Dd, 512, 0, stream>>>(Q, K, V, M, W1, b1, W2, b2,
                                                     ln1w, ln1b, ln2w, ln2b,
                                                     wsbf, use_ws, out);
}